// Round 6
// baseline (115.813 us; speedup 1.0000x reference)
//
#include <hip/hip_runtime.h>
#include <math.h>

// Differentiable-rasterizer forward: scalar sum((render - ref)^2).
// B=2, V=512, F=768, S=256 (derived from in_sizes; LDS sized for them).
//
// R6: cooperative launch failed under graph capture (R5). Two plain nodes:
//  k_tile  : ONE block per 16x16 tile, fully self-contained:
//            verts->LDS, bbox-cull all F faces (no divides), coeffs for
//            survivors only, packed-u64 argmin inner loop (exact tie-break),
//            reference-exact epilogue w/ inline tanh, f64 partial per tile.
//            No cross-block traffic, no zero-init, no atomics beyond LDS.
//  k_final : reduce 512 partials -> out[0] (deterministic).
// Fixed floor: harness ws-poison fill (~40us) is outside our control.

#define TILE  16
#define MAXV  512    // verts per batch
#define MAXF  768    // faces per batch

__global__ __launch_bounds__(256)
void k_tile(const float* __restrict__ verts, const int* __restrict__ faces,
            const float* __restrict__ Kmat, const float* __restrict__ Rmat,
            const float* __restrict__ tvec, const float* __restrict__ texin,
            const float* __restrict__ imref, double* __restrict__ partials,
            int B, int V, int F, int S)
{
    __shared__ float4         svdat[MAXV];     // 8 KB   (u, v, z)
    __shared__ float4         sf[MAXF * 3];    // 36 KB  survivor coeffs
    __shared__ unsigned short sidx[MAXF];      // 1.5 KB survivor face ids
    __shared__ int            scnt;
    __shared__ double         wsum[4];

    int tid    = threadIdx.x;
    int tileid = blockIdx.x;
    int tpi    = (S / TILE) * (S / TILE);
    int b      = tileid / tpi;
    int tr     = tileid - b * tpi;
    int ty     = tr / (S / TILE);
    int tx     = tr - ty * (S / TILE);
    int px     = tx * TILE + (tid & (TILE - 1));
    int py     = ty * TILE + (tid >> 4);
    float Sf   = (float)S;
    float pxf  = (2.0f*px + 1.0f - Sf) / Sf;
    float pyf  = (2.0f*py + 1.0f - Sf) / Sf;
    float xlo  = (2.0f*(tx*TILE)          + 1.0f - Sf) / Sf;
    float xhi  = (2.0f*(tx*TILE + TILE-1) + 1.0f - Sf) / Sf;
    float ylo  = (2.0f*(ty*TILE)          + 1.0f - Sf) / Sf;
    float yhi  = (2.0f*(ty*TILE + TILE-1) + 1.0f - Sf) / Sf;
    int lane = tid & 63, wid = tid >> 6;

    if (tid == 0) scnt = 0;

    // ---- project this batch's vertices into LDS (V/256 = 2 per thread)
    const float* R  = Rmat + b * 9;
    const float* Kb = Kmat + b * 9;
    const float* tb = tvec + b * 3;
    for (int i = tid; i < V && i < MAXV; i += 256) {
        const float* vp = verts + ((size_t)(b*V + i)) * 3;
        float vx = vp[0], vy = vp[1], vz = vp[2];
        float c0 = R[0]*vx + R[1]*vy + R[2]*vz + tb[0];
        float c1 = R[3]*vx + R[4]*vy + R[5]*vz + tb[1];
        float c2 = R[6]*vx + R[7]*vy + R[8]*vz + tb[2];
        float z  = c2;
        float zd = z + 1e-9f;
        float xh = c0 / zd;
        float yh = c1 / zd;
        float q0 = xh*Kb[0] + yh*Kb[1] + Kb[2];
        float q1 = xh*Kb[3] + yh*Kb[4] + Kb[5];
        float u = 2.0f * (q0 - 0.5f*Sf) / Sf;
        float v = 2.0f * ((Sf - q1) - 0.5f*Sf) / Sf;
        svdat[i] = make_float4(u, v, z, 0.0f);
    }
    __syncthreads();

    // ---- bbox cull over all F faces (no divides), ballot-compact into sidx
    for (int f = tid; f < F; f += 256) {
        const int* fp = faces + ((size_t)(b*F + f)) * 3;
        float4 P0 = svdat[fp[0]];
        float4 P1 = svdat[fp[1]];
        float4 P2 = svdat[fp[2]];
        float e1x = P1.x - P0.x, e1y = P1.y - P0.y;
        float e2x = P2.x - P0.x, e2y = P2.y - P0.y;
        float den = e1x*e2y - e2x*e1y;
        bool valid = fabsf(den) > 1e-8f;
        bool front = fminf(P0.z, fminf(P1.z, P2.z)) > 1e-9f;
        float xmn = fminf(P0.x, fminf(P1.x, P2.x));
        float xmx = fmaxf(P0.x, fmaxf(P1.x, P2.x));
        float ymn = fminf(P0.y, fminf(P1.y, P2.y));
        float ymx = fmaxf(P0.y, fmaxf(P1.y, P2.y));
        bool keep = valid && front &&
                    !(xmn > xhi || xmx < xlo || ymn > yhi || ymx < ylo);
        unsigned long long m = __ballot(keep);
        int base = 0;
        if (lane == 0 && m) base = atomicAdd(&scnt, __popcll(m));
        base = __shfl(base, 0, 64);
        if (keep) {
            int pos = base + __popcll(m & ((1ULL << lane) - 1ULL));
            sidx[pos] = (unsigned short)f;
        }
    }
    __syncthreads();
    int cnt = scnt;

    // ---- full coefficients for survivors only (~70 of 768)
    for (int j = tid; j < cnt; j += 256) {
        int f = sidx[j];
        const int* fp = faces + ((size_t)(b*F + f)) * 3;
        float4 P0 = svdat[fp[0]];
        float4 P1 = svdat[fp[1]];
        float4 P2 = svdat[fp[2]];
        float x0 = P0.x, y0 = P0.y, z0 = P0.z;
        float x1 = P1.x, y1 = P1.y, z1 = P1.z;
        float x2 = P2.x, y2 = P2.y, z2 = P2.z;
        float e1x = x1 - x0, e1y = y1 - y0;
        float e2x = x2 - x0, e2y = y2 - y0;
        float den = e1x*e2y - e2x*e1y;
        float dens = (fabsf(den) > 1e-8f) ? den : 1.0f;  // survivors: valid
        float A1 = e2y / dens, B1 = -e2x / dens;
        float C1 = -(x0*A1 + y0*B1);
        float A2 = -e1y / dens, B2 = e1x / dens;
        float C2 = -(x0*A2 + y0*B2);
        float A0 = -A1 - A2, B0 = -B1 - B2, C0 = 1.0f - C1 - C2;
        float rz0 = 1.0f/z0, rz1 = 1.0f/z1, rz2 = 1.0f/z2;
        float Az = A0*rz0 + A1*rz1 + A2*rz2;
        float Bz = B0*rz0 + B1*rz1 + B2*rz2;
        float Cz = C0*rz0 + C1*rz1 + C2*rz2;
        sf[j*3 + 0] = make_float4(A0, A1, A2, Az);
        sf[j*3 + 1] = make_float4(B0, B1, B2, Bz);
        sf[j*3 + 2] = make_float4(C0, C1, C2, Cz);
    }
    __syncthreads();

    // ---- inner loop: packed key (izbits<<32)|~fidx; max == argmin(depth)
    //      with exact first-index tie-break; init implements strict iz > EPS
    const unsigned long long initpk =
        ((unsigned long long)__float_as_uint(1e-9f) << 32) | 0xFFFFFFFFull;
    unsigned long long bestpk = initpk;
    #pragma unroll 2
    for (int j = 0; j < cnt; ++j) {
        int f = sidx[j];                  // wave-uniform broadcast
        float4 Av = sf[j*3 + 0];
        float4 Bv = sf[j*3 + 1];
        float4 Cv = sf[j*3 + 2];
        float w0 = fmaf(pxf, Av.x, fmaf(pyf, Bv.x, Cv.x));
        float w1 = fmaf(pxf, Av.y, fmaf(pyf, Bv.y, Cv.y));
        float w2 = fmaf(pxf, Av.z, fmaf(pyf, Bv.z, Cv.z));
        float iz = fmaf(pxf, Av.w, fmaf(pyf, Bv.w, Cv.w));
        float mn = fminf(w0, fminf(w1, w2));
        unsigned long long pk =
            ((unsigned long long)__float_as_uint(iz) << 32) |
            (unsigned long long)(~(unsigned)f);
        bool upd = (mn >= 0.0f) && (pk > bestpk);
        bestpk = upd ? pk : bestpk;
    }
    float bz  = __uint_as_float((unsigned)(bestpk >> 32));
    unsigned bidx = ~(unsigned)bestpk;    // all-miss -> 0 (argmin of all-inf)
    bool hit  = bz > 1e-9f;

    // ---- reference-exact epilogue for the chosen face
    const int* fp = faces + ((size_t)(b*F + bidx)) * 3;
    float4 P0 = svdat[fp[0]];
    float4 P1 = svdat[fp[1]];
    float4 P2 = svdat[fp[2]];
    float X0 = P0.x, Y0 = P0.y, Z0 = P0.z;
    float Z1 = P1.z, Z2 = P2.z;
    float E1x = P1.x - X0, E1y = P1.y - Y0;
    float E2x = P2.x - X0, E2y = P2.y - Y0;
    float den = E1x*E2y - E2x*E1y;
    float D = (fabsf(den) > 1e-8f) ? den : 1.0f;
    float dxp = pxf - X0, dyp = pyf - Y0;
    float W1 = (dxp*E2y - dyp*E2x) / D;
    float W2 = (E1x*dyp - E1y*dxp) / D;
    float W0 = 1.0f - W1 - W2;
    float q0 = W0 / Z0, q1 = W1 / Z1, q2 = W2 / Z2;
    float iz = fmaxf(q0 + q1 + q2, 1e-9f);
    float wp0 = fminf(fmaxf(q0 / iz, 0.0f), 1.0f);
    float wp1 = fminf(fmaxf(q1 / iz, 0.0f), 1.0f);
    float wp2 = fminf(fmaxf(q2 / iz, 0.0f), 1.0f);
    const float* T = texin + (size_t)bidx * 24;   // tanh applied inline
    float hitf = hit ? 1.0f : 0.0f;
    float a0l = 1.0f - wp0, a0h = wp0;
    float a1l = 1.0f - wp1, a1h = wp1;
    float a2l = 1.0f - wp2, a2h = wp2;
    float s = 0.0f;
    #pragma unroll
    for (int cc = 0; cc < 3; ++cc) {
        float t000 = tanhf(T[0  + cc]), t001 = tanhf(T[3  + cc]);
        float t010 = tanhf(T[6  + cc]), t011 = tanhf(T[9  + cc]);
        float t100 = tanhf(T[12 + cc]), t101 = tanhf(T[15 + cc]);
        float t110 = tanhf(T[18 + cc]), t111 = tanhf(T[21 + cc]);
        float col = a0l*(a1l*(a2l*t000 + a2h*t001) + a1h*(a2l*t010 + a2h*t011)) +
                    a0h*(a1l*(a2l*t100 + a2h*t101) + a1h*(a2l*t110 + a2h*t111));
        col *= hitf;
        float r = imref[(((size_t)b*3 + cc)*S + py)*S + px];
        float d = col - r;
        s = fmaf(d, d, s);
    }

    // ---- deterministic f64 block reduction -> per-tile partial
    double acc = (double)s;
    #pragma unroll
    for (int off = 32; off > 0; off >>= 1)
        acc += __shfl_down(acc, off, 64);
    if (lane == 0) wsum[wid] = acc;
    __syncthreads();
    if (tid == 0) partials[tileid] = wsum[0] + wsum[1] + wsum[2] + wsum[3];
}

__global__ void k_final(const double* __restrict__ partials, float* __restrict__ out, int n)
{
    int tid = threadIdx.x;
    double a = 0.0;
    for (int i = tid; i < n; i += 256) a += partials[i];
    #pragma unroll
    for (int off = 32; off > 0; off >>= 1)
        a += __shfl_down(a, off, 64);
    __shared__ double wsum[4];
    int lane = tid & 63, wid = tid >> 6;
    if (lane == 0) wsum[wid] = a;
    __syncthreads();
    if (tid == 0) out[0] = (float)(wsum[0] + wsum[1] + wsum[2] + wsum[3]);
}

extern "C" void kernel_launch(void* const* d_in, const int* in_sizes, int n_in,
                              void* d_out, int out_size, void* d_ws, size_t ws_size,
                              hipStream_t stream)
{
    const float* verts = (const float*)d_in[0];
    const int*   faces = (const int*)d_in[1];
    const float* Kmat  = (const float*)d_in[2];
    const float* Rmat  = (const float*)d_in[3];
    const float* tvec  = (const float*)d_in[4];
    const float* texin = (const float*)d_in[5];
    const float* imref = (const float*)d_in[6];

    int B = in_sizes[2] / 9;                    // K is (B,3,3)
    int V = in_sizes[0] / (3 * B);
    int F = in_sizes[1] / (3 * B);
    long ss = in_sizes[6] / (3L * B);           // image_ref is (B,3,S,S)
    int S = (int)(sqrt((double)ss) + 0.5);
    int ntiles = B * (S / TILE) * (S / TILE);

    double* partials = (double*)d_ws;           // ntiles * 8 bytes

    k_tile<<<ntiles, 256, 0, stream>>>(verts, faces, Kmat, Rmat, tvec,
                                       texin, imref, partials, B, V, F, S);
    k_final<<<1, 256, 0, stream>>>(partials, (float*)d_out, ntiles);
}

// Round 7
// 91.557 us; speedup vs baseline: 1.2649x; 1.2649x over previous
//
#include <hip/hip_runtime.h>
#include <math.h>

// Differentiable-rasterizer forward: scalar sum((render - ref)^2).
// B=2, V=512, F=768, S=256 (derived from in_sizes; LDS sized for V<=512).
//
// R7: R6 was latency-bound (512 blocks = 2 waves/SIMD, VALUBusy 14%).
// Same 2-node self-contained structure, but:
//  - TILE 16 -> 8: 2048 blocks (8 blocks/CU target, LDS ~21KB -> 7/CU)
//  - inner loop split across the 4 waves (j = wid mod 4), per-pixel merge
//    of 4 packed keys in LDS. Key carries ~fidx -> exact argmin-first-tie
//    regardless of processing order.
//  - epilogue parallelized over 192 threads (64 px x 3 channels).
// Fixed floor: harness 256MiB ws poison fill (~40us) every iteration.

#define TILE  8
#define MAXV  512    // verts per batch (LDS arrays sized for this)
#define CAP   256    // survivor capacity (avg ~67 for 8x8 tile; 20+ sigma)

__global__ __launch_bounds__(256, 8)
void k_tile(const float* __restrict__ verts, const int* __restrict__ faces,
            const float* __restrict__ Kmat, const float* __restrict__ Rmat,
            const float* __restrict__ tvec, const float* __restrict__ texin,
            const float* __restrict__ imref, double* __restrict__ partials,
            int B, int V, int F, int S)
{
    __shared__ float          su[MAXV], sv[MAXV], szl[MAXV];  // 6 KB
    __shared__ float4         sf[CAP * 3];                    // 12 KB
    __shared__ unsigned short sidx[CAP];                      // 0.5 KB
    __shared__ unsigned long long smax[64 * 4];               // 2 KB
    __shared__ unsigned long long skey[64];                   // 0.5 KB
    __shared__ int            scnt;
    __shared__ double         wsum[4];

    int tid    = threadIdx.x;
    int tileid = blockIdx.x;
    int tpr    = S / TILE;              // tiles per row
    int tpi    = tpr * tpr;             // tiles per image
    int b      = tileid / tpi;
    int tr     = tileid - b * tpi;
    int ty     = tr / tpr;
    int tx     = tr - ty * tpr;
    int lane   = tid & 63, wid = tid >> 6;
    float Sf   = (float)S;
    float xlo  = (2.0f*(tx*TILE)          + 1.0f - Sf) / Sf;
    float xhi  = (2.0f*(tx*TILE + TILE-1) + 1.0f - Sf) / Sf;
    float ylo  = (2.0f*(ty*TILE)          + 1.0f - Sf) / Sf;
    float yhi  = (2.0f*(ty*TILE + TILE-1) + 1.0f - Sf) / Sf;

    if (tid == 0) scnt = 0;

    // ---- project this batch's vertices into LDS (2 per thread)
    const float* R  = Rmat + b * 9;
    const float* Kb = Kmat + b * 9;
    const float* tb = tvec + b * 3;
    for (int i = tid; i < V && i < MAXV; i += 256) {
        const float* vp = verts + ((size_t)(b*V + i)) * 3;
        float vx = vp[0], vy = vp[1], vz = vp[2];
        float c0 = R[0]*vx + R[1]*vy + R[2]*vz + tb[0];
        float c1 = R[3]*vx + R[4]*vy + R[5]*vz + tb[1];
        float c2 = R[6]*vx + R[7]*vy + R[8]*vz + tb[2];
        float z  = c2;
        float zd = z + 1e-9f;
        float xh = c0 / zd;
        float yh = c1 / zd;
        float q0 = xh*Kb[0] + yh*Kb[1] + Kb[2];
        float q1 = xh*Kb[3] + yh*Kb[4] + Kb[5];
        su[i]  = 2.0f * (q0 - 0.5f*Sf) / Sf;
        sv[i]  = 2.0f * ((Sf - q1) - 0.5f*Sf) / Sf;
        szl[i] = z;
    }
    __syncthreads();

    // ---- bbox cull over all F faces (no divides), ballot-compact into sidx
    for (int f = tid; f < F; f += 256) {
        const int* fp = faces + ((size_t)(b*F + f)) * 3;
        int i0 = fp[0], i1 = fp[1], i2 = fp[2];
        float x0 = su[i0], y0 = sv[i0], z0 = szl[i0];
        float x1 = su[i1], y1 = sv[i1], z1 = szl[i1];
        float x2 = su[i2], y2 = sv[i2], z2 = szl[i2];
        float e1x = x1 - x0, e1y = y1 - y0;
        float e2x = x2 - x0, e2y = y2 - y0;
        float den = e1x*e2y - e2x*e1y;
        bool valid = fabsf(den) > 1e-8f;
        bool front = fminf(z0, fminf(z1, z2)) > 1e-9f;
        float xmn = fminf(x0, fminf(x1, x2)), xmx = fmaxf(x0, fmaxf(x1, x2));
        float ymn = fminf(y0, fminf(y1, y2)), ymx = fmaxf(y0, fmaxf(y1, y2));
        bool keep = valid && front &&
                    !(xmn > xhi || xmx < xlo || ymn > yhi || ymx < ylo);
        unsigned long long m = __ballot(keep);
        int base = 0;
        if (lane == 0 && m) base = atomicAdd(&scnt, __popcll(m));
        base = __shfl(base, 0, 64);
        if (keep) {
            int pos = base + __popcll(m & ((1ULL << lane) - 1ULL));
            if (pos < CAP) sidx[pos] = (unsigned short)f;
        }
    }
    __syncthreads();
    int cnt = min(scnt, CAP);

    // ---- full coefficients for survivors only
    for (int j = tid; j < cnt; j += 256) {
        int f = sidx[j];
        const int* fp = faces + ((size_t)(b*F + f)) * 3;
        int i0 = fp[0], i1 = fp[1], i2 = fp[2];
        float x0 = su[i0], y0 = sv[i0], z0 = szl[i0];
        float x1 = su[i1], y1 = sv[i1], z1 = szl[i1];
        float x2 = su[i2], y2 = sv[i2], z2 = szl[i2];
        float e1x = x1 - x0, e1y = y1 - y0;
        float e2x = x2 - x0, e2y = y2 - y0;
        float den = e1x*e2y - e2x*e1y;
        float dens = (fabsf(den) > 1e-8f) ? den : 1.0f;  // survivors valid
        float A1 = e2y / dens, B1 = -e2x / dens;
        float C1 = -(x0*A1 + y0*B1);
        float A2 = -e1y / dens, B2 = e1x / dens;
        float C2 = -(x0*A2 + y0*B2);
        float A0 = -A1 - A2, B0 = -B1 - B2, C0 = 1.0f - C1 - C2;
        float rz0 = 1.0f/z0, rz1 = 1.0f/z1, rz2 = 1.0f/z2;
        float Az = A0*rz0 + A1*rz1 + A2*rz2;
        float Bz = B0*rz0 + B1*rz1 + B2*rz2;
        float Cz = C0*rz0 + C1*rz1 + C2*rz2;
        sf[j*3 + 0] = make_float4(A0, A1, A2, Az);
        sf[j*3 + 1] = make_float4(B0, B1, B2, Bz);
        sf[j*3 + 2] = make_float4(C0, C1, C2, Cz);
        sidx[j] = (unsigned short)f;
    }
    __syncthreads();

    // ---- inner loop: this wave takes survivors j = wid (mod 4).
    //      lane <-> pixel of the 8x8 tile.
    int lx  = lane & (TILE - 1);
    int ly  = lane >> 3;
    int px  = tx * TILE + lx;
    int py  = ty * TILE + ly;
    float pxf = (2.0f*px + 1.0f - Sf) / Sf;
    float pyf = (2.0f*py + 1.0f - Sf) / Sf;
    const unsigned long long initpk =
        ((unsigned long long)__float_as_uint(1e-9f) << 32) | 0xFFFFFFFFull;
    unsigned long long bestpk = initpk;
    for (int j = wid; j < cnt; j += 4) {
        int f = sidx[j];                  // wave-uniform broadcast
        float4 Av = sf[j*3 + 0];
        float4 Bv = sf[j*3 + 1];
        float4 Cv = sf[j*3 + 2];
        float w0 = fmaf(pxf, Av.x, fmaf(pyf, Bv.x, Cv.x));
        float w1 = fmaf(pxf, Av.y, fmaf(pyf, Bv.y, Cv.y));
        float w2 = fmaf(pxf, Av.z, fmaf(pyf, Bv.z, Cv.z));
        float iz = fmaf(pxf, Av.w, fmaf(pyf, Bv.w, Cv.w));
        float mn = fminf(w0, fminf(w1, w2));
        unsigned long long pk =
            ((unsigned long long)__float_as_uint(iz) << 32) |
            (unsigned long long)(~(unsigned)f);
        bool upd = (mn >= 0.0f) && (pk > bestpk);
        bestpk = upd ? pk : bestpk;
    }
    smax[lane*4 + wid] = bestpk;
    __syncthreads();
    if (tid < 64) {
        unsigned long long k0 = smax[tid*4 + 0], k1 = smax[tid*4 + 1];
        unsigned long long k2 = smax[tid*4 + 2], k3 = smax[tid*4 + 3];
        k0 = k0 > k1 ? k0 : k1;
        k2 = k2 > k3 ? k2 : k3;
        skey[tid] = k0 > k2 ? k0 : k2;
    }
    __syncthreads();

    // ---- epilogue: 192 threads = 64 px x 3 channels, reference-exact
    float s = 0.0f;
    int lpx = tid & 63;
    int cc  = tid >> 6;                   // 0..3; cc==3 idle
    if (cc < 3) {
        int elx = lpx & (TILE - 1), ely = lpx >> 3;
        int epx = tx * TILE + elx,  epy = ty * TILE + ely;
        float epxf = (2.0f*epx + 1.0f - Sf) / Sf;
        float epyf = (2.0f*epy + 1.0f - Sf) / Sf;
        unsigned long long pk = skey[lpx];
        float bz = __uint_as_float((unsigned)(pk >> 32));
        unsigned bidx = ~(unsigned)pk;    // all-miss -> 0
        bool hit = bz > 1e-9f;
        const int* fp = faces + ((size_t)(b*F + bidx)) * 3;
        int i0 = fp[0], i1 = fp[1], i2 = fp[2];
        float X0 = su[i0], Y0 = sv[i0], Z0 = szl[i0];
        float Z1 = szl[i1], Z2 = szl[i2];
        float E1x = su[i1] - X0, E1y = sv[i1] - Y0;
        float E2x = su[i2] - X0, E2y = sv[i2] - Y0;
        float den = E1x*E2y - E2x*E1y;
        float D = (fabsf(den) > 1e-8f) ? den : 1.0f;
        float dxp = epxf - X0, dyp = epyf - Y0;
        float W1 = (dxp*E2y - dyp*E2x) / D;
        float W2 = (E1x*dyp - E1y*dxp) / D;
        float W0 = 1.0f - W1 - W2;
        float q0 = W0 / Z0, q1 = W1 / Z1, q2 = W2 / Z2;
        float iz = fmaxf(q0 + q1 + q2, 1e-9f);
        float wp0 = fminf(fmaxf(q0 / iz, 0.0f), 1.0f);
        float wp1 = fminf(fmaxf(q1 / iz, 0.0f), 1.0f);
        float wp2 = fminf(fmaxf(q2 / iz, 0.0f), 1.0f);
        const float* T = texin + (size_t)bidx * 24;   // tanh inline
        float a0l = 1.0f - wp0, a0h = wp0;
        float a1l = 1.0f - wp1, a1h = wp1;
        float a2l = 1.0f - wp2, a2h = wp2;
        float t000 = tanhf(T[0  + cc]), t001 = tanhf(T[3  + cc]);
        float t010 = tanhf(T[6  + cc]), t011 = tanhf(T[9  + cc]);
        float t100 = tanhf(T[12 + cc]), t101 = tanhf(T[15 + cc]);
        float t110 = tanhf(T[18 + cc]), t111 = tanhf(T[21 + cc]);
        float col = a0l*(a1l*(a2l*t000 + a2h*t001) + a1h*(a2l*t010 + a2h*t011)) +
                    a0h*(a1l*(a2l*t100 + a2h*t101) + a1h*(a2l*t110 + a2h*t111));
        col *= hit ? 1.0f : 0.0f;
        float r = imref[(((size_t)b*3 + cc)*S + epy)*S + epx];
        float d = col - r;
        s = d * d;
    }

    // ---- deterministic f64 block reduction -> per-tile partial
    double acc = (double)s;
    #pragma unroll
    for (int off = 32; off > 0; off >>= 1)
        acc += __shfl_down(acc, off, 64);
    if (lane == 0) wsum[wid] = acc;
    __syncthreads();
    if (tid == 0) partials[tileid] = wsum[0] + wsum[1] + wsum[2] + wsum[3];
}

__global__ void k_final(const double* __restrict__ partials, float* __restrict__ out, int n)
{
    int tid = threadIdx.x;
    double a = 0.0;
    for (int i = tid; i < n; i += 256) a += partials[i];
    #pragma unroll
    for (int off = 32; off > 0; off >>= 1)
        a += __shfl_down(a, off, 64);
    __shared__ double wsum[4];
    int lane = tid & 63, wid = tid >> 6;
    if (lane == 0) wsum[wid] = a;
    __syncthreads();
    if (tid == 0) out[0] = (float)(wsum[0] + wsum[1] + wsum[2] + wsum[3]);
}

extern "C" void kernel_launch(void* const* d_in, const int* in_sizes, int n_in,
                              void* d_out, int out_size, void* d_ws, size_t ws_size,
                              hipStream_t stream)
{
    const float* verts = (const float*)d_in[0];
    const int*   faces = (const int*)d_in[1];
    const float* Kmat  = (const float*)d_in[2];
    const float* Rmat  = (const float*)d_in[3];
    const float* tvec  = (const float*)d_in[4];
    const float* texin = (const float*)d_in[5];
    const float* imref = (const float*)d_in[6];

    int B = in_sizes[2] / 9;                    // K is (B,3,3)
    int V = in_sizes[0] / (3 * B);
    int F = in_sizes[1] / (3 * B);
    long ss = in_sizes[6] / (3L * B);           // image_ref is (B,3,S,S)
    int S = (int)(sqrt((double)ss) + 0.5);
    int ntiles = B * (S / TILE) * (S / TILE);

    double* partials = (double*)d_ws;           // ntiles * 8 bytes

    k_tile<<<ntiles, 256, 0, stream>>>(verts, faces, Kmat, Rmat, tvec,
                                       texin, imref, partials, B, V, F, S);
    k_final<<<1, 256, 0, stream>>>(partials, (float*)d_out, ntiles);
}